// Round 4
// baseline (841.732 us; speedup 1.0000x reference)
//
#include <hip/hip_runtime.h>

#define QLEN 1024
#define BSZ  4
#define DM   512
#define NH   8
#define DH   64
#define FFD  2048

static constexpr float LN_EPS = 1e-5f;

// ---------------------------------------------------------------------------
// Relative positional encoding rows for rel = 0..1023:
// pe[rel][f] = sin(rel * invf[f])        f in [0,256)
//              cos(rel * invf[f-256])    f in [256,512)
// invf[f0] = 10000^(-2*f0/512) = exp(-f0 * ln(10000)/256)
// ---------------------------------------------------------------------------
__global__ void pe_kernel(float* __restrict__ pe) {
  int idx = blockIdx.x * 256 + threadIdx.x;
  if (idx >= QLEN * DM) return;
  int r  = idx >> 9;           // rel position
  int f  = idx & (DM - 1);
  int f0 = f & 255;
  float invf = __expf(-(float)f0 * (9.210340371976184f / 256.0f));
  float arg  = (float)r * invf;
  pe[idx] = (f < 256) ? sinf(arg) : cosf(arg);
}

// ---------------------------------------------------------------------------
// Tiled f32 GEMM, 64x64 tile, 256 threads, 4x4 per thread.
// BT=0: C[M][N] = A[M][K] * B[K][N]      (B row-major, k-major)
// BT=1: C[M][N] = A[M][K] * B[N][K]^T    (B row-major, n-major; dot of rows)
// EPI: 0 none, 1 +bias, 2 +bias then exact gelu
// M % 64 == 0, N % 64 == 0, K % 16 == 0 assumed.
// ---------------------------------------------------------------------------
template <int BT, int EPI>
__global__ __launch_bounds__(256) void gemm64(
    const float* __restrict__ A, const float* __restrict__ B,
    const float* __restrict__ bias, float* __restrict__ C,
    int M, int N, int K) {
  __shared__ float As[16][68];   // [k][m]
  __shared__ float Bs[16][68];   // [k][n]
  const int t  = threadIdx.x;
  const int tx = t & 15, ty = t >> 4;
  const int bm = blockIdx.y * 64, bn = blockIdx.x * 64;
  float acc[4][4] = {{0.f, 0.f, 0.f, 0.f}, {0.f, 0.f, 0.f, 0.f},
                     {0.f, 0.f, 0.f, 0.f}, {0.f, 0.f, 0.f, 0.f}};

  for (int k0 = 0; k0 < K; k0 += 16) {
    {
      const int r = t >> 2, k4 = (t & 3) << 2;
      const float4 a = *reinterpret_cast<const float4*>(
          A + (size_t)(bm + r) * K + k0 + k4);
      As[k4 + 0][r] = a.x; As[k4 + 1][r] = a.y;
      As[k4 + 2][r] = a.z; As[k4 + 3][r] = a.w;
    }
    if (BT == 0) {
      const int kk = t >> 4, c4 = (t & 15) << 2;
      const float4 bv = *reinterpret_cast<const float4*>(
          B + (size_t)(k0 + kk) * N + bn + c4);
      Bs[kk][c4 + 0] = bv.x; Bs[kk][c4 + 1] = bv.y;
      Bs[kk][c4 + 2] = bv.z; Bs[kk][c4 + 3] = bv.w;
    } else {
      const int c = t >> 2, k4 = (t & 3) << 2;
      const float4 bv = *reinterpret_cast<const float4*>(
          B + (size_t)(bn + c) * K + k0 + k4);
      Bs[k4 + 0][c] = bv.x; Bs[k4 + 1][c] = bv.y;
      Bs[k4 + 2][c] = bv.z; Bs[k4 + 3][c] = bv.w;
    }
    __syncthreads();
#pragma unroll
    for (int kk = 0; kk < 16; ++kk) {
      const float4 a4 = *reinterpret_cast<const float4*>(&As[kk][ty << 2]);
      const float4 b4 = *reinterpret_cast<const float4*>(&Bs[kk][tx << 2]);
      acc[0][0] += a4.x * b4.x; acc[0][1] += a4.x * b4.y;
      acc[0][2] += a4.x * b4.z; acc[0][3] += a4.x * b4.w;
      acc[1][0] += a4.y * b4.x; acc[1][1] += a4.y * b4.y;
      acc[1][2] += a4.y * b4.z; acc[1][3] += a4.y * b4.w;
      acc[2][0] += a4.z * b4.x; acc[2][1] += a4.z * b4.y;
      acc[2][2] += a4.z * b4.z; acc[2][3] += a4.z * b4.w;
      acc[3][0] += a4.w * b4.x; acc[3][1] += a4.w * b4.y;
      acc[3][2] += a4.w * b4.z; acc[3][3] += a4.w * b4.w;
    }
    __syncthreads();
  }
#pragma unroll
  for (int i = 0; i < 4; ++i) {
    const size_t row = (size_t)(bm + (ty << 2) + i) * N;
#pragma unroll
    for (int j = 0; j < 4; ++j) {
      const int c = bn + (tx << 2) + j;
      float v = acc[i][j];
      if (EPI >= 1) v += bias[c];
      if (EPI == 2) v = 0.5f * v * (1.0f + erff(v * 0.70710678118654752f));
      C[row + c] = v;
    }
  }
}

// ---------------------------------------------------------------------------
// Fused causal flash attention with XLNet relative-position term.
// Grid: (32 i-tiles, 32 b*n). Block: 256 threads.
// Tile: 32 q-rows x 32 k-cols. Each thread: one q-row (r=t>>3),
// 4 score cols (c = (t&7)+8*jj), 8 output dims (d = (t&7)*8..+7).
// score[i][j] = 0.125*(qa[i].k[j] + qb[i].kprel[i-j]),  masked j>i.
// ---------------------------------------------------------------------------
__global__ __launch_bounds__(256) void attn_kernel(
    const float* __restrict__ qh, const float* __restrict__ kh,
    const float* __restrict__ vh, const float* __restrict__ kprel,
    const float* __restrict__ rwb, const float* __restrict__ rrb,
    float* __restrict__ av) {
  __shared__ float qa[32][68];
  __shared__ float qb[32][68];
  __shared__ float ks[32][68];
  __shared__ float vs[32][68];
  __shared__ float kp[63][68];
  __shared__ float ps[32][37];

  const int t  = threadIdx.x;
  const int it = blockIdx.x;
  const int bn = blockIdx.y;
  const int b  = bn >> 3, n = bn & 7;
  const int i0 = it * 32;
  const int r  = t >> 3;
  const int cg = t & 7;

  const float4* qh4    = reinterpret_cast<const float4*>(qh);
  const float4* kh4    = reinterpret_cast<const float4*>(kh);
  const float4* vh4    = reinterpret_cast<const float4*>(vh);
  const float4* kprel4 = reinterpret_cast<const float4*>(kprel);
  const float4* rwb4   = reinterpret_cast<const float4*>(rwb);
  const float4* rrb4   = reinterpret_cast<const float4*>(rrb);

  // stage q tiles (+biases) once
#pragma unroll
  for (int q = 0; q < 2; ++q) {
    const int e = t + 256 * q;
    const int rr = e >> 4, d4 = e & 15;
    const float4 qv = qh4[(size_t)((i0 + rr) * BSZ + b) * 128 + n * 16 + d4];
    const float4 w  = rwb4[n * 16 + d4];
    const float4 u  = rrb4[n * 16 + d4];
    float4 x;
    x.x = qv.x + w.x; x.y = qv.y + w.y; x.z = qv.z + w.z; x.w = qv.w + w.w;
    *reinterpret_cast<float4*>(&qa[rr][d4 << 2]) = x;
    x.x = qv.x + u.x; x.y = qv.y + u.y; x.z = qv.z + u.z; x.w = qv.w + u.w;
    *reinterpret_cast<float4*>(&qb[rr][d4 << 2]) = x;
  }

  float m_run = -1e30f, l_run = 0.f;
  float o[8] = {0.f, 0.f, 0.f, 0.f, 0.f, 0.f, 0.f, 0.f};

  for (int jt = 0; jt <= it; ++jt) {
    const int j0 = jt * 32;
    const int D  = i0 - j0;
    __syncthreads();  // prev-iter PV done (and q staging visible on iter 0)
    // stage K, V tiles
#pragma unroll
    for (int q = 0; q < 2; ++q) {
      const int e = t + 256 * q;
      const int rr = e >> 4, d4 = e & 15;
      const size_t g = (size_t)((j0 + rr) * BSZ + b) * 128 + n * 16 + d4;
      *reinterpret_cast<float4*>(&ks[rr][d4 << 2]) = kh4[g];
      *reinterpret_cast<float4*>(&vs[rr][d4 << 2]) = vh4[g];
    }
    // stage kprel band: row u holds rel = D-31+u, u in [0,63)
#pragma unroll
    for (int q = 0; q < 4; ++q) {
      const int e = t + 256 * q;
      if (e < 63 * 16) {
        const int u = e >> 4, d4 = e & 15;
        const int rel = D - 31 + u;
        float4 pv;
        if (rel >= 0) pv = kprel4[(size_t)rel * 128 + n * 16 + d4];
        else { pv.x = 0.f; pv.y = 0.f; pv.z = 0.f; pv.w = 0.f; }
        *reinterpret_cast<float4*>(&kp[u][d4 << 2]) = pv;
      }
    }
    __syncthreads();

    // scores
    float s[4] = {0.f, 0.f, 0.f, 0.f};
    for (int d4 = 0; d4 < 16; ++d4) {
      const float4 a4 = *reinterpret_cast<const float4*>(&qa[r][d4 << 2]);
      const float4 b4 = *reinterpret_cast<const float4*>(&qb[r][d4 << 2]);
#pragma unroll
      for (int jj = 0; jj < 4; ++jj) {
        const int c = cg + 8 * jj;
        const float4 k4 = *reinterpret_cast<const float4*>(&ks[c][d4 << 2]);
        const float4 p4 = *reinterpret_cast<const float4*>(&kp[r - c + 31][d4 << 2]);
        s[jj] += a4.x * k4.x + a4.y * k4.y + a4.z * k4.z + a4.w * k4.w +
                 b4.x * p4.x + b4.y * p4.y + b4.z * p4.z + b4.w * p4.w;
      }
    }
    float tmax = -1e30f;
#pragma unroll
    for (int jj = 0; jj < 4; ++jj) {
      const int c = cg + 8 * jj;
      s[jj] = (D == 0 && c > r) ? -1e30f : s[jj] * 0.125f;
      tmax = fmaxf(tmax, s[jj]);
    }
    tmax = fmaxf(tmax, __shfl_xor(tmax, 1));
    tmax = fmaxf(tmax, __shfl_xor(tmax, 2));
    tmax = fmaxf(tmax, __shfl_xor(tmax, 4));
    const float m_new = fmaxf(m_run, tmax);
    const float corr  = __expf(m_run - m_new);
    float p[4], psum = 0.f;
#pragma unroll
    for (int jj = 0; jj < 4; ++jj) { p[jj] = __expf(s[jj] - m_new); psum += p[jj]; }
    psum += __shfl_xor(psum, 1);
    psum += __shfl_xor(psum, 2);
    psum += __shfl_xor(psum, 4);
    l_run = l_run * corr + psum;
    m_run = m_new;
#pragma unroll
    for (int q = 0; q < 8; ++q) o[q] *= corr;
#pragma unroll
    for (int jj = 0; jj < 4; ++jj) ps[r][cg + 8 * jj] = p[jj];
    __syncthreads();
    // PV accumulate: this thread owns d = cg*8 .. cg*8+7 of row r
#pragma unroll 8
    for (int j = 0; j < 32; ++j) {
      const float pv = ps[r][j];
      const float4 v0 = *reinterpret_cast<const float4*>(&vs[j][cg * 8]);
      const float4 v1 = *reinterpret_cast<const float4*>(&vs[j][cg * 8 + 4]);
      o[0] += pv * v0.x; o[1] += pv * v0.y; o[2] += pv * v0.z; o[3] += pv * v0.w;
      o[4] += pv * v1.x; o[5] += pv * v1.y; o[6] += pv * v1.z; o[7] += pv * v1.w;
    }
  }

  const float inv = 1.f / l_run;
  float4 o0, o1;
  o0.x = o[0] * inv; o0.y = o[1] * inv; o0.z = o[2] * inv; o0.w = o[3] * inv;
  o1.x = o[4] * inv; o1.y = o[5] * inv; o1.z = o[6] * inv; o1.w = o[7] * inv;
  float4* av4 = reinterpret_cast<float4*>(av);
  const size_t g = (size_t)((i0 + r) * BSZ + b) * 128 + n * 16 + cg * 2;
  av4[g]     = o0;
  av4[g + 1] = o1;
}

// ---------------------------------------------------------------------------
// LayerNorm kernels (one block of 256 per row of 512)
// ---------------------------------------------------------------------------
__device__ __forceinline__ float blk_sum(float v, volatile float* sb) {
  v += __shfl_xor(v, 1);  v += __shfl_xor(v, 2);  v += __shfl_xor(v, 4);
  v += __shfl_xor(v, 8);  v += __shfl_xor(v, 16); v += __shfl_xor(v, 32);
  const int t = threadIdx.x;
  if ((t & 63) == 0) sb[t >> 6] = v;
  __syncthreads();
  v = sb[0] + sb[1] + sb[2] + sb[3];
  __syncthreads();
  return v;
}

__global__ __launch_bounds__(256) void ln_res_kernel(
    const float* __restrict__ a, const float* __restrict__ res,
    const float* __restrict__ g, const float* __restrict__ be,
    float* __restrict__ out) {
  __shared__ float sb[4];
  const int row = blockIdx.x, t = threadIdx.x;
  const float* pa = a + (size_t)row * DM;
  const float* pr = res + (size_t)row * DM;
  const float x0 = pa[t] + pr[t];
  const float x1 = pa[t + 256] + pr[t + 256];
  const float mu = blk_sum(x0 + x1, sb) * (1.f / DM);
  const float d0 = x0 - mu, d1 = x1 - mu;
  const float var = blk_sum(d0 * d0 + d1 * d1, sb) * (1.f / DM);
  const float inv = rsqrtf(var + LN_EPS);
  out[(size_t)row * DM + t]       = d0 * inv * g[t] + be[t];
  out[(size_t)row * DM + t + 256] = d1 * inv * g[t + 256] + be[t + 256];
}

__global__ __launch_bounds__(256) void ln_final_kernel(
    const float* __restrict__ y, const float* __restrict__ xres,
    const float* __restrict__ g2, const float* __restrict__ be2,
    const float* __restrict__ gf, const float* __restrict__ bf,
    float* __restrict__ out) {
  __shared__ float sb[4];
  const int row = blockIdx.x, t = threadIdx.x;
  const float* py = y + (size_t)row * DM;
  const float* px = xres + (size_t)row * DM;
  const float x0 = py[t] + px[t];
  const float x1 = py[t + 256] + px[t + 256];
  const float mu = blk_sum(x0 + x1, sb) * (1.f / DM);
  const float d0 = x0 - mu, d1 = x1 - mu;
  const float var = blk_sum(d0 * d0 + d1 * d1, sb) * (1.f / DM);
  const float inv = rsqrtf(var + LN_EPS);
  const float z0 = d0 * inv * g2[t] + be2[t];
  const float z1 = d1 * inv * g2[t + 256] + be2[t + 256];
  const float mu2 = blk_sum(z0 + z1, sb) * (1.f / DM);
  const float e0 = z0 - mu2, e1 = z1 - mu2;
  const float var2 = blk_sum(e0 * e0 + e1 * e1, sb) * (1.f / DM);
  const float inv2 = rsqrtf(var2 + LN_EPS);
  out[(size_t)row * DM + t]       = e0 * inv2 * gf[t] + bf[t];
  out[(size_t)row * DM + t + 256] = e1 * inv2 * gf[t + 256] + bf[t + 256];
}

// ---------------------------------------------------------------------------
extern "C" void kernel_launch(void* const* d_in, const int* in_sizes, int n_in,
                              void* d_out, int out_size, void* d_ws, size_t ws_size,
                              hipStream_t stream) {
  const float* src = (const float*)d_in[0];
  const float* q_w = (const float*)d_in[1];
  const float* k_w = (const float*)d_in[2];
  const float* v_w = (const float*)d_in[3];
  const float* r_w = (const float*)d_in[4];
  const float* o_w = (const float*)d_in[5];
  const float* rwb = (const float*)d_in[6];
  const float* rrb = (const float*)d_in[7];
  const float* w1  = (const float*)d_in[8];
  const float* b1  = (const float*)d_in[9];
  const float* w2  = (const float*)d_in[10];
  const float* b2  = (const float*)d_in[11];
  const float* g1  = (const float*)d_in[12];
  const float* be1 = (const float*)d_in[13];
  const float* g2  = (const float*)d_in[14];
  const float* be2 = (const float*)d_in[15];
  const float* gf  = (const float*)d_in[16];
  const float* bf  = (const float*)d_in[17];

  float* ws = (float*)d_ws;
  // layout (floats); h reuses the dead pe/qh/kh/vh/kprel/av region,
  // y2 reuses the dead ao region. Peak = 13,631,488 floats = 54.5 MB.
  float* pe    = ws;                    //  524288
  float* qhb   = ws + 524288;           // 2097152
  float* khb   = qhb + 2097152;
  float* vhb   = khb + 2097152;
  float* kprel = vhb + 2097152;         //  524288  (ends 7,340,032)
  float* av    = kprel + 524288;        // 2097152  (ends 9,437,184)
  float* ao    = av + 2097152;          // 2097152  (ends 11,534,336)
  float* x1    = ao + 2097152;          // 2097152  (ends 13,631,488)
  float* h     = ws;                    // 8388608  (dead region reuse)
  float* y2    = ws + 9437184;          // 2097152  (= ao region, dead)
  float* outp  = (float*)d_out;

  pe_kernel<<<dim3(2048), 256, 0, stream>>>(pe);

  gemm64<0, 0><<<dim3(8, 64), 256, 0, stream>>>(src, q_w, nullptr, qhb, 4096, 512, 512);
  gemm64<0, 0><<<dim3(8, 64), 256, 0, stream>>>(src, k_w, nullptr, khb, 4096, 512, 512);
  gemm64<0, 0><<<dim3(8, 64), 256, 0, stream>>>(src, v_w, nullptr, vhb, 4096, 512, 512);
  gemm64<0, 0><<<dim3(8, 16), 256, 0, stream>>>(pe, r_w, nullptr, kprel, 1024, 512, 512);

  attn_kernel<<<dim3(32, 32), 256, 0, stream>>>(qhb, khb, vhb, kprel, rwb, rrb, av);

  gemm64<1, 0><<<dim3(8, 64), 256, 0, stream>>>(av, o_w, nullptr, ao, 4096, 512, 512);
  ln_res_kernel<<<dim3(4096), 256, 0, stream>>>(ao, src, g1, be1, x1);

  gemm64<1, 2><<<dim3(32, 64), 256, 0, stream>>>(x1, w1, b1, h, 4096, 2048, 512);
  gemm64<1, 1><<<dim3(8, 64), 256, 0, stream>>>(h, w2, b2, y2, 4096, 512, 2048);

  ln_final_kernel<<<dim3(4096), 256, 0, stream>>>(y2, x1, g2, be2, gf, bf, outp);
}

// Round 5
// 213.810 us; speedup vs baseline: 3.9368x; 3.9368x over previous
//
#include <hip/hip_runtime.h>

#define QLEN 1024
#define BSZ  4
#define DM   512
#define NH   8
#define DH   64
#define FFD  2048

static constexpr float LN_EPS = 1e-5f;

typedef __attribute__((ext_vector_type(8))) short short8_t;  // 8 bf16 (4 VGPRs)
typedef __attribute__((ext_vector_type(4))) float f32x4;

__device__ __forceinline__ ushort f2b(float f) {
  uint u = __float_as_uint(f);
  return (ushort)((u + 0x7FFFu + ((u >> 16) & 1u)) >> 16);   // RNE
}
__device__ __forceinline__ float b2f(ushort h) {
  return __uint_as_float(((uint)h) << 16);
}

// ---------------------------------------------------------------------------
// Relative positional encoding rows (bf16): rel = 0..1023
// ---------------------------------------------------------------------------
__global__ void pe_kernel(ushort* __restrict__ pe) {
  int idx = blockIdx.x * 256 + threadIdx.x;
  if (idx >= QLEN * DM) return;
  int r  = idx >> 9;
  int f  = idx & (DM - 1);
  int f0 = f & 255;
  float invf = __expf(-(float)f0 * (9.210340371976184f / 256.0f));
  float arg  = (float)r * invf;
  pe[idx] = f2b((f < 256) ? sinf(arg) : cosf(arg));
}

// ---------------------------------------------------------------------------
// f32 -> bf16 convert, 8 elems/thread
// ---------------------------------------------------------------------------
__global__ void cvt8_kernel(const float* __restrict__ in, ushort* __restrict__ out, int n8) {
  int idx = blockIdx.x * 256 + threadIdx.x;
  if (idx >= n8) return;
  const float4 f0 = *reinterpret_cast<const float4*>(in + (size_t)idx * 8);
  const float4 f1 = *reinterpret_cast<const float4*>(in + (size_t)idx * 8 + 4);
  uint p0 = f2b(f0.x) | ((uint)f2b(f0.y) << 16);
  uint p1 = f2b(f0.z) | ((uint)f2b(f0.w) << 16);
  uint p2 = f2b(f1.x) | ((uint)f2b(f1.y) << 16);
  uint p3 = f2b(f1.z) | ((uint)f2b(f1.w) << 16);
  int4 st; st.x = (int)p0; st.y = (int)p1; st.z = (int)p2; st.w = (int)p3;
  *reinterpret_cast<int4*>(out + (size_t)idx * 8) = st;
}

// ---------------------------------------------------------------------------
// Transpose 512x512 f32 [h][nd] -> bf16 [nd][h].  z: 0,1,2 = q,k,v -> qkvw
// rows z*512+nd ; z=3 = r_w -> rwT.
// ---------------------------------------------------------------------------
__global__ __launch_bounds__(256) void trans512_kernel(
    const float* __restrict__ qw, const float* __restrict__ kw,
    const float* __restrict__ vw, const float* __restrict__ rw,
    ushort* __restrict__ qkvw, ushort* __restrict__ rwT) {
  __shared__ float tile[32][33];
  const int z = blockIdx.z;
  const float* in = (z == 0) ? qw : (z == 1) ? kw : (z == 2) ? vw : rw;
  const int nd0 = blockIdx.x * 32, h0 = blockIdx.y * 32;
  const int tx = threadIdx.x & 31, ty = threadIdx.x >> 5;
#pragma unroll
  for (int k = 0; k < 4; ++k)
    tile[ty + 8 * k][tx] = in[(size_t)(h0 + ty + 8 * k) * 512 + nd0 + tx];
  __syncthreads();
  ushort* out = (z < 3) ? (qkvw + (size_t)z * 512 * 512) : rwT;
#pragma unroll
  for (int k = 0; k < 4; ++k)
    out[(size_t)(nd0 + ty + 8 * k) * 512 + h0 + tx] = f2b(tile[tx][ty + 8 * k]);
}

// ---------------------------------------------------------------------------
// V transpose: vT[head][d][seq] (bf16) from qkv[token][1024 + n*64 + d]
// grid: (seq-tile 16, head 32), block 256
// ---------------------------------------------------------------------------
__global__ __launch_bounds__(256) void vtrans_kernel(
    const ushort* __restrict__ qkv, ushort* __restrict__ vT) {
  __shared__ ushort vt[64][72];   // row stride 144B (16-aligned)
  const int t = threadIdx.x;
  const int head = blockIdx.y;
  const int b = head >> 3, n = head & 7;
  const int s0 = blockIdx.x * 64;
#pragma unroll
  for (int ro = 0; ro < 2; ++ro) {
    const int s = (t >> 3) + 32 * ro;
    const int d8 = t & 7;
    int4 rd = *reinterpret_cast<const int4*>(
        qkv + (size_t)((s0 + s) * 4 + b) * 1536 + 1024 + n * 64 + d8 * 8);
    *reinterpret_cast<int4*>(&vt[s][d8 * 8]) = rd;
  }
  __syncthreads();
#pragma unroll
  for (int ro = 0; ro < 2; ++ro) {
    const int d = (t >> 3) + 32 * ro;
    const int s8 = t & 7;
    uint pk[4];
#pragma unroll
    for (int q = 0; q < 4; ++q) {
      ushort e0 = vt[s8 * 8 + 2 * q][d];
      ushort e1 = vt[s8 * 8 + 2 * q + 1][d];
      pk[q] = (uint)e0 | ((uint)e1 << 16);
    }
    int4 st; st.x = (int)pk[0]; st.y = (int)pk[1]; st.z = (int)pk[2]; st.w = (int)pk[3];
    *reinterpret_cast<int4*>(vT + (size_t)(head * 64 + d) * 1024 + s0 + s8 * 8) = st;
  }
}

// ---------------------------------------------------------------------------
// bf16 MFMA GEMM: C[M][N] = A[M][K] * B[N][K]^T, f32 accum.
// Tiles: BM=64, BN=128, BK=32. 256 threads = 4 waves, each 32x64 out
// (2x4 frags of 16x16).  LDS row stride 40 bf16 (80B) -> ~2-way conflicts.
// EPI: 0 = bf16 out; 1 = f32 out; 2 = bf16 out + bias + exact gelu;
//      3 = f32 out + bias.
// ---------------------------------------------------------------------------
template <int EPI>
__global__ __launch_bounds__(256) void gemm_bf16(
    const ushort* __restrict__ A, const ushort* __restrict__ B,
    const float* __restrict__ bias, void* __restrict__ Cout,
    int M, int N, int K) {
  __shared__ ushort As[64 * 40];
  __shared__ ushort Bs[128 * 40];
  const int t = threadIdx.x;
  const int w = t >> 6, l = t & 63;
  const int lc = l & 15, lq = l >> 4;
  const int bm = blockIdx.y * 64, bn = blockIdx.x * 128;
  const int wr = (w >> 1) * 32, wc = (w & 1) * 64;
  const int sr = t >> 2, sk = (t & 3) * 8;      // staging row / k-offset

  f32x4 acc[2][4];
#pragma unroll
  for (int i = 0; i < 2; ++i)
#pragma unroll
    for (int j = 0; j < 4; ++j) acc[i][j] = (f32x4){0.f, 0.f, 0.f, 0.f};

  for (int k0 = 0; k0 < K; k0 += 32) {
    int4 a_v = *reinterpret_cast<const int4*>(A + (size_t)(bm + sr) * K + k0 + sk);
    int4 b0v = *reinterpret_cast<const int4*>(B + (size_t)(bn + sr) * K + k0 + sk);
    int4 b1v = *reinterpret_cast<const int4*>(B + (size_t)(bn + 64 + sr) * K + k0 + sk);
    __syncthreads();
    *reinterpret_cast<int4*>(As + sr * 40 + sk) = a_v;
    *reinterpret_cast<int4*>(Bs + sr * 40 + sk) = b0v;
    *reinterpret_cast<int4*>(Bs + (64 + sr) * 40 + sk) = b1v;
    __syncthreads();
    short8_t af[2], bf[4];
#pragma unroll
    for (int mf = 0; mf < 2; ++mf)
      af[mf] = *reinterpret_cast<const short8_t*>(As + (wr + mf * 16 + lc) * 40 + lq * 8);
#pragma unroll
    for (int nf = 0; nf < 4; ++nf)
      bf[nf] = *reinterpret_cast<const short8_t*>(Bs + (wc + nf * 16 + lc) * 40 + lq * 8);
#pragma unroll
    for (int mf = 0; mf < 2; ++mf)
#pragma unroll
      for (int nf = 0; nf < 4; ++nf)
        acc[mf][nf] = __builtin_amdgcn_mfma_f32_16x16x32_bf16(af[mf], bf[nf], acc[mf][nf], 0, 0, 0);
  }

#pragma unroll
  for (int mf = 0; mf < 2; ++mf)
#pragma unroll
    for (int nf = 0; nf < 4; ++nf) {
      const int col = bn + wc + nf * 16 + lc;
#pragma unroll
      for (int reg = 0; reg < 4; ++reg) {
        const int row = bm + wr + mf * 16 + lq * 4 + reg;
        float v = acc[mf][nf][reg];
        if (EPI == 2 || EPI == 3) v += bias[col];
        if (EPI == 2) v = 0.5f * v * (1.0f + erff(v * 0.70710678118654752f));
        if (EPI == 0 || EPI == 2)
          ((ushort*)Cout)[(size_t)row * N + col] = f2b(v);
        else
          ((float*)Cout)[(size_t)row * N + col] = v;
      }
    }
}

// ---------------------------------------------------------------------------
// MFMA flash attention with XLNet relative term.
// Grid (32 it, 32 head), block 256 = 4 waves. Wave w processes j-tiles
// {w, w+4, ...}; deterministic 4-way flash merge at the end.
// S[r][c] = 0.125*(qa.K[j] + G[r][r-c+31]),  G[r][u] = qb . kprel[D-31+u].
// ---------------------------------------------------------------------------
__global__ __launch_bounds__(256) void attn_mfma(
    const ushort* __restrict__ qkv,    // [4096][1536]
    const ushort* __restrict__ kprel,  // [1024][512]
    const ushort* __restrict__ vT,     // [32][64][1024]
    const float* __restrict__ rwb, const float* __restrict__ rrb,
    ushort* __restrict__ av) {         // [4096][512]
  __shared__ float  Gb[4][32 * 66];
  __shared__ ushort Pb[4][32 * 40];
  __shared__ float  obuf[32 * 68];
  __shared__ float  mlb[4][32][2];

  const int t = threadIdx.x, w = t >> 6, l = t & 63;
  const int it = 31 - blockIdx.x;      // heavy blocks dispatch first
  const int head = blockIdx.y;
  const int b = head >> 3, n = head & 7;
  const int i0 = it * 32;
  const int lc = l & 15, lq = l >> 4;

  // ---- Q fragments with biases (qa = q + r_w_bias, qb = q + r_r_bias)
  short8_t qa[2][2], qb[2][2];
#pragma unroll
  for (int mf = 0; mf < 2; ++mf)
#pragma unroll
    for (int kc = 0; kc < 2; ++kc) {
      const int tok = (i0 + mf * 16 + lc) * 4 + b;
      const int kof = kc * 32 + lq * 8;
      int4 qv = *reinterpret_cast<const int4*>(qkv + (size_t)tok * 1536 + n * 64 + kof);
      uint xs[4] = {(uint)qv.x, (uint)qv.y, (uint)qv.z, (uint)qv.w};
      short8_t a_, b_;
#pragma unroll
      for (int q = 0; q < 4; ++q) {
        float e0 = b2f((ushort)(xs[q] & 0xffffu));
        float e1 = b2f((ushort)(xs[q] >> 16));
        a_[2 * q]     = (short)f2b(e0 + rwb[n * 64 + kof + 2 * q]);
        a_[2 * q + 1] = (short)f2b(e1 + rwb[n * 64 + kof + 2 * q + 1]);
        b_[2 * q]     = (short)f2b(e0 + rrb[n * 64 + kof + 2 * q]);
        b_[2 * q + 1] = (short)f2b(e1 + rrb[n * 64 + kof + 2 * q + 1]);
      }
      qa[mf][kc] = a_; qb[mf][kc] = b_;
    }

  float m_run[2][4], l_run[2][4];
  f32x4 oacc[2][4];
#pragma unroll
  for (int mf = 0; mf < 2; ++mf)
#pragma unroll
    for (int reg = 0; reg < 4; ++reg) { m_run[mf][reg] = -1e30f; l_run[mf][reg] = 0.f; }
#pragma unroll
  for (int mf = 0; mf < 2; ++mf)
#pragma unroll
    for (int nf = 0; nf < 4; ++nf) oacc[mf][nf] = (f32x4){0.f, 0.f, 0.f, 0.f};

  float* gw = Gb[w];
  ushort* pw = Pb[w];
  const int nj = it + 1;

  for (int jt = w; jt < nj; jt += 4) {
    const int j0 = jt * 32;
    const int D = i0 - j0;

    // ---- AC = QA . K^T  (2x2 frags)
    f32x4 sacc[2][2];
#pragma unroll
    for (int mf = 0; mf < 2; ++mf)
#pragma unroll
      for (int nf = 0; nf < 2; ++nf) sacc[mf][nf] = (f32x4){0.f, 0.f, 0.f, 0.f};
#pragma unroll
    for (int kc = 0; kc < 2; ++kc)
#pragma unroll
      for (int nf = 0; nf < 2; ++nf) {
        const int tok = (j0 + nf * 16 + lc) * 4 + b;
        int4 kv = *reinterpret_cast<const int4*>(
            qkv + (size_t)tok * 1536 + 512 + n * 64 + kc * 32 + lq * 8);
        short8_t kf = __builtin_bit_cast(short8_t, kv);
#pragma unroll
        for (int mf = 0; mf < 2; ++mf)
          sacc[mf][nf] = __builtin_amdgcn_mfma_f32_16x16x32_bf16(qa[mf][kc], kf, sacc[mf][nf], 0, 0, 0);
      }

    // ---- G = QB . kprel-band^T  (2x4 frags, cols u = 0..63)
    f32x4 gacc[2][4];
#pragma unroll
    for (int mf = 0; mf < 2; ++mf)
#pragma unroll
      for (int nf = 0; nf < 4; ++nf) gacc[mf][nf] = (f32x4){0.f, 0.f, 0.f, 0.f};
#pragma unroll
    for (int kc = 0; kc < 2; ++kc)
#pragma unroll
      for (int nf = 0; nf < 4; ++nf) {
        int rho = D - 31 + nf * 16 + lc;
        rho = (rho < 0) ? 0 : (rho > 1023 ? 1023 : rho);
        int4 pv = *reinterpret_cast<const int4*>(
            kprel + (size_t)rho * 512 + n * 64 + kc * 32 + lq * 8);
        short8_t pf = __builtin_bit_cast(short8_t, pv);
#pragma unroll
        for (int mf = 0; mf < 2; ++mf)
          gacc[mf][nf] = __builtin_amdgcn_mfma_f32_16x16x32_bf16(qb[mf][kc], pf, gacc[mf][nf], 0, 0, 0);
      }

    // ---- spill G to wave-private LDS (C-layout write, conflict-free)
#pragma unroll
    for (int mf = 0; mf < 2; ++mf)
#pragma unroll
      for (int nf = 0; nf < 4; ++nf)
#pragma unroll
        for (int reg = 0; reg < 4; ++reg)
          gw[(mf * 16 + lq * 4 + reg) * 66 + nf * 16 + lc] = gacc[mf][nf][reg];

    // ---- S assembly (diagonal gather) + online softmax per row
#pragma unroll
    for (int mf = 0; mf < 2; ++mf)
#pragma unroll
      for (int reg = 0; reg < 4; ++reg) {
        const int r = mf * 16 + lq * 4 + reg;
        const int c0 = lc, c1 = 16 + lc;
        float s0 = (sacc[mf][0][reg] + gw[r * 66 + (r - c0 + 31)]) * 0.125f;
        float s1 = (sacc[mf][1][reg] + gw[r * 66 + (r - c1 + 31)]) * 0.125f;
        if (D == 0) {
          if (c0 > r) s0 = -1e30f;
          if (c1 > r) s1 = -1e30f;
        }
        float tm = fmaxf(s0, s1);
        tm = fmaxf(tm, __shfl_xor(tm, 1));
        tm = fmaxf(tm, __shfl_xor(tm, 2));
        tm = fmaxf(tm, __shfl_xor(tm, 4));
        tm = fmaxf(tm, __shfl_xor(tm, 8));
        const float mn = fmaxf(m_run[mf][reg], tm);
        const float corr = __expf(m_run[mf][reg] - mn);
        const float p0 = __expf(s0 - mn), p1 = __expf(s1 - mn);
        float ps = p0 + p1;
        ps += __shfl_xor(ps, 1);
        ps += __shfl_xor(ps, 2);
        ps += __shfl_xor(ps, 4);
        ps += __shfl_xor(ps, 8);
        l_run[mf][reg] = l_run[mf][reg] * corr + ps;
        m_run[mf][reg] = mn;
#pragma unroll
        for (int nf = 0; nf < 4; ++nf) oacc[mf][nf][reg] *= corr;
        pw[r * 40 + c0] = f2b(p0);
        pw[r * 40 + c1] = f2b(p1);
      }

    // ---- PV: O += P . V  (A-frags from LDS, B-frags from global vT)
    short8_t pa[2];
#pragma unroll
    for (int mf = 0; mf < 2; ++mf)
      pa[mf] = *reinterpret_cast<const short8_t*>(pw + (mf * 16 + lc) * 40 + lq * 8);
#pragma unroll
    for (int nf = 0; nf < 4; ++nf) {
      int4 vv = *reinterpret_cast<const int4*>(
          vT + (size_t)(head * 64 + nf * 16 + lc) * 1024 + j0 + lq * 8);
      short8_t vf = __builtin_bit_cast(short8_t, vv);
#pragma unroll
      for (int mf = 0; mf < 2; ++mf)
        oacc[mf][nf] = __builtin_amdgcn_mfma_f32_16x16x32_bf16(pa[mf], vf, oacc[mf][nf], 0, 0, 0);
    }
  }

  // ---- 4-way flash merge (deterministic)
  if (lc == 0) {
#pragma unroll
    for (int mf = 0; mf < 2; ++mf)
#pragma unroll
      for (int reg = 0; reg < 4; ++reg) {
        const int r = mf * 16 + lq * 4 + reg;
        mlb[w][r][0] = m_run[mf][reg];
        mlb[w][r][1] = l_run[mf][reg];
      }
  }
  __syncthreads();
  for (int i = t; i < 32 * 68; i += 256) obuf[i] = 0.f;
  __syncthreads();

  float scl[2][4];
#pragma unroll
  for (int mf = 0; mf < 2; ++mf)
#pragma unroll
    for (int reg = 0; reg < 4; ++reg) {
      const int r = mf * 16 + lq * 4 + reg;
      const float m0 = mlb[0][r][0], m1 = mlb[1][r][0], m2 = mlb[2][r][0], m3 = mlb[3][r][0];
      const float ms = fmaxf(fmaxf(m0, m1), fmaxf(m2, m3));
      scl[mf][reg] = __expf(mlb[w][r][0] - ms);
    }
#pragma unroll
  for (int ww = 0; ww < 4; ++ww) {
    if (w == ww) {
#pragma unroll
      for (int mf = 0; mf < 2; ++mf)
#pragma unroll
        for (int nf = 0; nf < 4; ++nf)
#pragma unroll
          for (int reg = 0; reg < 4; ++reg) {
            const int r = mf * 16 + lq * 4 + reg;
            obuf[r * 68 + nf * 16 + lc] += scl[mf][reg] * oacc[mf][nf][reg];
          }
    }
    __syncthreads();
  }

  {
    const int r = t >> 3, d0 = (t & 7) * 8;
    const float m0 = mlb[0][r][0], m1 = mlb[1][r][0], m2 = mlb[2][r][0], m3 = mlb[3][r][0];
    const float ms = fmaxf(fmaxf(m0, m1), fmaxf(m2, m3));
    const float ls = mlb[0][r][1] * __expf(m0 - ms) + mlb[1][r][1] * __expf(m1 - ms) +
                     mlb[2][r][1] * __expf(m2 - ms) + mlb[3][r][1] * __expf(m3 - ms);
    const float inv = 1.f / ls;
    uint pk[4];
#pragma unroll
    for (int q = 0; q < 4; ++q) {
      ushort e0 = f2b(obuf[r * 68 + d0 + 2 * q] * inv);
      ushort e1 = f2b(obuf[r * 68 + d0 + 2 * q + 1] * inv);
      pk[q] = (uint)e0 | ((uint)e1 << 16);
    }
    int4 st; st.x = (int)pk[0]; st.y = (int)pk[1]; st.z = (int)pk[2]; st.w = (int)pk[3];
    const int tok = (i0 + r) * 4 + b;
    *reinterpret_cast<int4*>(av + (size_t)tok * 512 + n * 64 + d0) = st;
  }
}

// ---------------------------------------------------------------------------
// LayerNorm kernels (f32 math; ln_res also emits bf16 copy for FFN1)
// ---------------------------------------------------------------------------
__device__ __forceinline__ float blk_sum(float v, volatile float* sb) {
  v += __shfl_xor(v, 1);  v += __shfl_xor(v, 2);  v += __shfl_xor(v, 4);
  v += __shfl_xor(v, 8);  v += __shfl_xor(v, 16); v += __shfl_xor(v, 32);
  const int t = threadIdx.x;
  if ((t & 63) == 0) sb[t >> 6] = v;
  __syncthreads();
  v = sb[0] + sb[1] + sb[2] + sb[3];
  __syncthreads();
  return v;
}

__global__ __launch_bounds__(256) void ln_res_kernel(
    const float* __restrict__ a, const float* __restrict__ res,
    const float* __restrict__ g, const float* __restrict__ be,
    float* __restrict__ out, ushort* __restrict__ outb) {
  __shared__ float sb[4];
  const int row = blockIdx.x, t = threadIdx.x;
  const float* pa = a + (size_t)row * DM;
  const float* pr = res + (size_t)row * DM;
  const float x0 = pa[t] + pr[t];
  const float x1 = pa[t + 256] + pr[t + 256];
  const float mu = blk_sum(x0 + x1, sb) * (1.f / DM);
  const float d0 = x0 - mu, d1 = x1 - mu;
  const float var = blk_sum(d0 * d0 + d1 * d1, sb) * (1.f / DM);
  const float inv = rsqrtf(var + LN_EPS);
  const float z0 = d0 * inv * g[t] + be[t];
  const float z1 = d1 * inv * g[t + 256] + be[t + 256];
  out[(size_t)row * DM + t] = z0;
  out[(size_t)row * DM + t + 256] = z1;
  outb[(size_t)row * DM + t] = f2b(z0);
  outb[(size_t)row * DM + t + 256] = f2b(z1);
}

__global__ __launch_bounds__(256) void ln_final_kernel(
    const float* __restrict__ y, const float* __restrict__ xres,
    const float* __restrict__ g2, const float* __restrict__ be2,
    const float* __restrict__ gf, const float* __restrict__ bf,
    float* __restrict__ out) {
  __shared__ float sb[4];
  const int row = blockIdx.x, t = threadIdx.x;
  const float* py = y + (size_t)row * DM;
  const float* px = xres + (size_t)row * DM;
  const float x0 = py[t] + px[t];
  const float x1 = py[t + 256] + px[t + 256];
  const float mu = blk_sum(x0 + x1, sb) * (1.f / DM);
  const float d0 = x0 - mu, d1 = x1 - mu;
  const float var = blk_sum(d0 * d0 + d1 * d1, sb) * (1.f / DM);
  const float inv = rsqrtf(var + LN_EPS);
  const float z0 = d0 * inv * g2[t] + be2[t];
  const float z1 = d1 * inv * g2[t + 256] + be2[t + 256];
  const float mu2 = blk_sum(z0 + z1, sb) * (1.f / DM);
  const float e0 = z0 - mu2, e1 = z1 - mu2;
  const float var2 = blk_sum(e0 * e0 + e1 * e1, sb) * (1.f / DM);
  const float inv2 = rsqrtf(var2 + LN_EPS);
  out[(size_t)row * DM + t]       = e0 * inv2 * gf[t] + bf[t];
  out[(size_t)row * DM + t + 256] = e1 * inv2 * gf[t + 256] + bf[t + 256];
}

// ---------------------------------------------------------------------------
extern "C" void kernel_launch(void* const* d_in, const int* in_sizes, int n_in,
                              void* d_out, int out_size, void* d_ws, size_t ws_size,
                              hipStream_t stream) {
  const float* src = (const float*)d_in[0];
  const float* q_w = (const float*)d_in[1];
  const float* k_w = (const float*)d_in[2];
  const float* v_w = (const float*)d_in[3];
  const float* r_w = (const float*)d_in[4];
  const float* o_w = (const float*)d_in[5];
  const float* rwb = (const float*)d_in[6];
  const float* rrb = (const float*)d_in[7];
  const float* w1  = (const float*)d_in[8];
  const float* b1  = (const float*)d_in[9];
  const float* w2  = (const float*)d_in[10];
  const float* b2  = (const float*)d_in[11];
  const float* g1  = (const float*)d_in[12];
  const float* be1 = (const float*)d_in[13];
  const float* g2  = (const float*)d_in[14];
  const float* be2 = (const float*)d_in[15];
  const float* gf  = (const float*)d_in[16];
  const float* bf  = (const float*)d_in[17];

  char* ws = (char*)d_ws;
  const size_t MB = 1024 * 1024;
  ushort* srcb  = (ushort*)(ws + 0);                 // 4 MB
  ushort* qkvw  = (ushort*)(ws + 4 * MB);            // 1.5 MB
  ushort* rwT   = (ushort*)(ws + 5 * MB + 512 * 1024);  // 0.5 MB
  ushort* owb   = (ushort*)(ws + 6 * MB);            // 0.5 MB
  ushort* w1b   = (ushort*)(ws + 6 * MB + 512 * 1024);  // 2 MB
  ushort* w2b   = (ushort*)(ws + 8 * MB + 512 * 1024);  // 2 MB
  ushort* peb   = (ushort*)(ws + 10 * MB + 512 * 1024); // 1 MB
  ushort* qkv   = (ushort*)(ws + 11 * MB + 512 * 1024); // 12 MB
  ushort* kprel = (ushort*)(ws + 23 * MB + 512 * 1024); // 1 MB
  ushort* vT    = (ushort*)(ws + 24 * MB + 512 * 1024); // 4 MB
  ushort* av    = (ushort*)(ws + 28 * MB + 512 * 1024); // 4 MB
  float*  ao    = (float*) (ws + 32 * MB + 512 * 1024); // 8 MB
  float*  x1    = (float*) (ws + 40 * MB + 512 * 1024); // 8 MB
  ushort* x1b   = (ushort*)(ws + 48 * MB + 512 * 1024); // 4 MB
  ushort* h     = (ushort*)(ws + 11 * MB + 512 * 1024); // 16 MB (reuse qkv+kprel+vT)
  float*  y2    = (float*) (ws + 32 * MB + 512 * 1024); // 8 MB (reuse ao)
  float*  outp  = (float*)d_out;

  // precompute / conversions
  pe_kernel<<<dim3(2048), 256, 0, stream>>>(peb);
  cvt8_kernel<<<dim3(1024), 256, 0, stream>>>(src, srcb, 262144);
  cvt8_kernel<<<dim3(128), 256, 0, stream>>>(o_w, owb, 32768);
  cvt8_kernel<<<dim3(512), 256, 0, stream>>>(w1, w1b, 131072);
  cvt8_kernel<<<dim3(512), 256, 0, stream>>>(w2, w2b, 131072);
  trans512_kernel<<<dim3(16, 16, 4), 256, 0, stream>>>(q_w, k_w, v_w, r_w, qkvw, rwT);

  // fused QKV projection + kprel projection
  gemm_bf16<0><<<dim3(12, 64), 256, 0, stream>>>(srcb, qkvw, nullptr, qkv, 4096, 1536, 512);
  gemm_bf16<0><<<dim3(4, 16), 256, 0, stream>>>(peb, rwT, nullptr, kprel, 1024, 512, 512);
  vtrans_kernel<<<dim3(16, 32), 256, 0, stream>>>(qkv, vT);

  attn_mfma<<<dim3(32, 32), 256, 0, stream>>>(qkv, kprel, vT, rwb, rrb, av);

  gemm_bf16<1><<<dim3(4, 64), 256, 0, stream>>>(av, owb, nullptr, ao, 4096, 512, 512);
  ln_res_kernel<<<dim3(4096), 256, 0, stream>>>(ao, src, g1, be1, x1, x1b);

  gemm_bf16<2><<<dim3(16, 64), 256, 0, stream>>>(x1b, w1b, b1, h, 4096, 2048, 512);
  gemm_bf16<3><<<dim3(4, 64), 256, 0, stream>>>(h, w2b, b2, y2, 4096, 512, 2048);

  ln_final_kernel<<<dim3(4096), 256, 0, stream>>>(y2, x1, g2, be2, gf, bf, outp);
}